// Round 4
// baseline (573.536 us; speedup 1.0000x reference)
//
#include <hip/hip_runtime.h>
#include <hip/hip_bf16.h>
#include <math.h>

// Problem constants
#define NRES     64
#define EXPRN    4
#define B_TOT    256           // NRES * EXPRN flattened rows
#define NC       1025          // N_COEFFS
#define NF       128           // N_FRAMES
#define HOP      1024
#define MHALF    1024          // half-size complex FFT length (WINDOW/2)
#define NTHREADS 512
#define CHUNK    64            // frames per block
#define NCHUNK   2             // chunks per row

// Padded LDS index: breaks bitrev scatter's 32-way bank conflict into 2-way.
__device__ __forceinline__ int F(int a) { return a + (a >> 5); }

__device__ __forceinline__ uint32_t rotl32(uint32_t x, int r) {
  return (x << r) | (x >> (32 - r));
}

// Bit-exact reproduction of jax.random.uniform(jax.random.key(42),
// (256,128,1025), minval=-1, maxval=1) at flat element index i, under the
// modern default jax_threefry_partitionable=True path:
//   counts = 64-bit iota -> (hi=0, lo=i); bits = lane0 ^ lane1 of
//   threefry2x32((0,42), (0, i)).
__device__ __forceinline__ float tf_noise(uint32_t i) {
  const uint32_t k0 = 0u, k1 = 42u;
  const uint32_t k2 = 0x1BD11BDAu ^ k0 ^ k1;
  uint32_t x0 = 0u + k0;       // counts_hi + ks[0]
  uint32_t x1 = i + k1;        // counts_lo + ks[1]
#define TF_ROUND(r) { x0 += x1; x1 = rotl32(x1, r); x1 ^= x0; }
  TF_ROUND(13) TF_ROUND(15) TF_ROUND(26) TF_ROUND(6)
  x0 += k1; x1 += k2 + 1u;
  TF_ROUND(17) TF_ROUND(29) TF_ROUND(16) TF_ROUND(24)
  x0 += k2; x1 += k0 + 2u;
  TF_ROUND(13) TF_ROUND(15) TF_ROUND(26) TF_ROUND(6)
  x0 += k0; x1 += k1 + 3u;
  TF_ROUND(17) TF_ROUND(29) TF_ROUND(16) TF_ROUND(24)
  x0 += k1; x1 += k2 + 4u;
  TF_ROUND(13) TF_ROUND(15) TF_ROUND(26) TF_ROUND(6)
  x0 += k2; x1 += k0 + 5u;
#undef TF_ROUND
  uint32_t bits = x0 ^ x1;
  // float in [1,2) - 1 -> [0,1); * 2 - 1 -> [-1,1). All steps exact in fp32.
  float f = __uint_as_float((bits >> 9) | 0x3f800000u) - 1.0f;
  return f * 2.0f - 1.0f;
}

__global__ __launch_bounds__(NTHREADS)
void resblock_kernel(const float* __restrict__ amp,
                     const float* __restrict__ phase,
                     const float* __restrict__ decay,
                     const float* __restrict__ pdith,
                     float* __restrict__ out) {
  __shared__ float sp[NC], dth[NC], lgc[NC], smN[NC], phi[NC];
  __shared__ float xr[NC], xi[NC];
  __shared__ float zr[MHALF + MHALF / 32], zi[MHALF + MHALF / 32];
  __shared__ float twc[MHALF], tws[MHALF];   // e^{+i*pi*k/1024}

  const int tid = threadIdx.x;
  const int b = blockIdx.x;          // row = r*4 + e
  const int j = blockIdx.y;          // frame chunk
  const int t0 = j * CHUNK;
  const int tstart = (j == 0) ? 0 : (t0 - 1);   // one carry-only warmup frame
  const int tend = t0 + CHUNK;
  const int r = b >> 2, e = b & 3;
  const int base = r * (NC * EXPRN) + e;        // input layout (64,1025,4)

  const float PI_F = 3.14159265358979323846f;

  // Per-coefficient setup + noise prefix to chunk start.
  for (int c = tid; c < NC; c += NTHREADS) {
    const int gi = base + c * EXPRN;
    const float a  = amp[gi];
    const float p  = phase[gi];
    const float d0 = decay[gi];
    const float pd = pdith[gi];
    const float sig = 1.0f / (1.0f + expf(-d0));
    const float coeff = 0.5f + 0.495f * sig;   // BASE_RES + sig*0.5*0.99
    lgc[c] = logf(coeff);
    smN[c] = a * a * (1.0f / 1024.0f);         // fold 1/M irfft norm into mags
    const float spv = tanhf(p) * PI_F;
    sp[c] = spv;
    const float dv = tanhf(pd);
    dth[c] = dv;
    float acc = 0.0f;
    uint32_t idx = (uint32_t)(b * NF) * (uint32_t)NC + (uint32_t)c;
    for (int s = 0; s < tstart; ++s) { acc += tf_noise(idx); idx += NC; }
    phi[c] = (float)tstart * spv + dv * acc;
  }
  for (int k = tid; k < MHALF; k += NTHREADS) {
    float sn, cs;
    sincosf(PI_F * (float)k * (1.0f / 1024.0f), &sn, &cs);
    twc[k] = cs; tws[k] = sn;
  }
  __syncthreads();

  float carry0 = 0.0f, carry1 = 0.0f;          // OLA carry for m=tid, tid+512
  const long outbase = (long)b * (NF * HOP);

  for (int t = tstart; t < tend; ++t) {
    // ---- spectrum for frame t ----
    for (int c = tid; c < NC; c += NTHREADS) {
      const float nz = tf_noise((uint32_t)((b * NF + t) * NC + c));
      const float ph = phi[c] + sp[c] + dth[c] * nz;
      phi[c] = ph;
      const float mag = smN[c] * expf((float)(t + 1) * lgc[c]);
      float sn, cs;
      sincosf(ph, &sn, &cs);
      xr[c] = mag * cs;
      xi[c] = (c == 0 || c == MHALF) ? 0.0f : mag * sn;  // c2r ignores DC/Nyq imag
    }
    __syncthreads();

    // ---- pack to half-size complex spectrum Z, bit-reversed into zr/zi ----
    for (int k = tid; k < MHALF; k += NTHREADS) {
      const float x0r = xr[k],         x0i = xi[k];
      const float x1r = xr[MHALF - k], x1i = xi[MHALF - k];
      const float ar = 0.5f * (x0r + x1r);
      const float ai = 0.5f * (x0i - x1i);
      const float dr = x0r - x1r;
      const float di = x0i + x1i;
      const float ct = twc[k], st = tws[k];
      const float br = -0.5f * (dr * st + di * ct);
      const float bi =  0.5f * (dr * ct - di * st);
      const int kr = (int)(__brev((uint32_t)k) >> 22);
      zr[F(kr)] = ar + br;
      zi[F(kr)] = ai + bi;
    }
    __syncthreads();

    // ---- 1024-pt radix-2 DIT inverse FFT (e^{+i}), 512 butterflies/stage ----
    for (int s = 1; s <= 10; ++s) {
      const int half = 1 << (s - 1);
      const int q  = tid >> (s - 1);
      const int rr = tid & (half - 1);
      const int i0 = (q << s) | rr;
      const int i1 = i0 + half;
      const int ti = rr << (11 - s);            // r * 2048/len
      const float wc = twc[ti], ws = tws[ti];
      const float ur = zr[F(i0)], ui = zi[F(i0)];
      const float vr = zr[F(i1)], vi = zi[F(i1)];
      const float tr  = vr * wc - vi * ws;
      const float tii = vr * ws + vi * wc;
      zr[F(i0)] = ur + tr;   zi[F(i0)] = ui + tii;
      zr[F(i1)] = ur - tr;   zi[F(i1)] = ui - tii;
      __syncthreads();
    }

    // ---- overlap-add: out[m] = frame[m] + prev_frame[1024+m]; carry 2nd half
    {
      const int m0 = tid, m1 = tid + 512;
      const float xa0 = (m0 & 1) ? zi[F(m0 >> 1)] : zr[F(m0 >> 1)];
      const float xa1 = (m1 & 1) ? zi[F(m1 >> 1)] : zr[F(m1 >> 1)];
      const float xb0 = (m0 & 1) ? zi[F((m0 + HOP) >> 1)] : zr[F((m0 + HOP) >> 1)];
      const float xb1 = (m1 & 1) ? zi[F((m1 + HOP) >> 1)] : zr[F((m1 + HOP) >> 1)];
      if (t >= t0) {
        const long ob = outbase + (long)t * HOP;
        out[ob + m0] = xa0 + carry0;
        out[ob + m1] = xa1 + carry1;
      }
      carry0 = xb0;
      carry1 = xb1;
    }
    // No trailing sync needed: next frame's zr/zi writes are ordered behind the
    // __syncthreads() after the xr/xi spectrum stage.
  }
}

extern "C" void kernel_launch(void* const* d_in, const int* in_sizes, int n_in,
                              void* d_out, int out_size, void* d_ws, size_t ws_size,
                              hipStream_t stream) {
  (void)in_sizes; (void)n_in; (void)d_ws; (void)ws_size; (void)out_size;
  const float* amp   = (const float*)d_in[0];
  const float* phase = (const float*)d_in[1];
  const float* decay = (const float*)d_in[2];
  const float* pdith = (const float*)d_in[3];
  float* out = (float*)d_out;

  dim3 grid(B_TOT, NCHUNK);
  dim3 block(NTHREADS);
  hipLaunchKernelGGL(resblock_kernel, grid, block, 0, stream,
                     amp, phase, decay, pdith, out);
}

// Round 5
// 408.056 us; speedup vs baseline: 1.4055x; 1.4055x over previous
//
#include <hip/hip_runtime.h>
#include <math.h>

// Problem constants
#define NRES     64
#define EXPRN    4
#define B_TOT    256           // NRES * EXPRN flattened rows
#define NC       1025          // N_COEFFS
#define NF       128           // N_FRAMES
#define HOP      1024
#define MHALF    1024          // half-size complex FFT length (WINDOW/2)
#define NTHREADS 512
#define CHUNK    32            // frames per block
#define NCHUNK   4             // chunks per row

// Padded LDS index: breaks bitrev scatter's 32-way bank conflict into 2-way.
__device__ __forceinline__ int F(int a) { return a + (a >> 5); }

__device__ __forceinline__ uint32_t rotl32(uint32_t x, int r) {
  return (x << r) | (x >> (32 - r));
}

// Bit-exact jax.random.uniform(key(42), minval=-1, maxval=1) under the modern
// default jax_threefry_partitionable=True path: bits = x0 ^ x1 of
// threefry2x32((0,42), (hi=0, lo=i)).
__device__ __forceinline__ float tf_noise(uint32_t i) {
  const uint32_t k0 = 0u, k1 = 42u;
  const uint32_t k2 = 0x1BD11BDAu ^ k0 ^ k1;
  uint32_t x0 = 0u + k0;
  uint32_t x1 = i + k1;
#define TF_ROUND(r) { x0 += x1; x1 = rotl32(x1, r); x1 ^= x0; }
  TF_ROUND(13) TF_ROUND(15) TF_ROUND(26) TF_ROUND(6)
  x0 += k1; x1 += k2 + 1u;
  TF_ROUND(17) TF_ROUND(29) TF_ROUND(16) TF_ROUND(24)
  x0 += k2; x1 += k0 + 2u;
  TF_ROUND(13) TF_ROUND(15) TF_ROUND(26) TF_ROUND(6)
  x0 += k0; x1 += k1 + 3u;
  TF_ROUND(17) TF_ROUND(29) TF_ROUND(16) TF_ROUND(24)
  x0 += k1; x1 += k2 + 4u;
  TF_ROUND(13) TF_ROUND(15) TF_ROUND(26) TF_ROUND(6)
  x0 += k2; x1 += k0 + 5u;
#undef TF_ROUND
  uint32_t bits = x0 ^ x1;
  float f = __uint_as_float((bits >> 9) | 0x3f800000u) - 1.0f;  // [0,1) exact
  return f * 2.0f - 1.0f;
}

__global__ __launch_bounds__(NTHREADS, 6)
void resblock_kernel(const float* __restrict__ amp,
                     const float* __restrict__ phase,
                     const float* __restrict__ decay,
                     const float* __restrict__ pdith,
                     float* __restrict__ out) {
  __shared__ float zr[MHALF + MHALF / 32], zi[MHALF + MHALF / 32];
  __shared__ float2 tw[MHALF];   // packed per-stage twiddles: tw[half+rr] = e^{+i*pi*rr/half}

  const int tid = threadIdx.x;
  const int k = tid;                 // owns spectrum pair (k, 1024-k)
  const int b = blockIdx.x;          // row = r*4 + e
  const int j = blockIdx.y;          // frame chunk
  const int t0 = j * CHUNK;
  const int tstart = (j == 0) ? 0 : (t0 - 1);   // one carry-only warmup frame
  const int tend = t0 + CHUNK;
  const int r = b >> 2, e = b & 3;
  const int base = r * (NC * EXPRN) + e;        // input layout (64,1025,4)
  const float PI_F = 3.14159265358979323846f;

  // ---- packed twiddle table (conflict-free stage reads) ----
  for (int i = tid; i < MHALF; i += NTHREADS) {
    float cs = 1.0f, sn = 0.0f;
    if (i > 0) {
      const int half = 1 << (31 - __clz(i));
      const int rr = i - half;
      float ang = PI_F * (float)rr / (float)half;
      sincosf(ang, &sn, &cs);
    }
    tw[i] = make_float2(cs, sn);
  }

  // ---- per-thread register chains: A = coeff k, B = coeff 1024-k, M = 512 (tid 0) ----
  float spA, dthA, coefA, magA, phiA; uint32_t idxA;
  float spB, dthB, coefB, magB, phiB; uint32_t idxB;
  float spM = 0, dthM = 0, coefM = 1, magM = 0, phiM = 0; uint32_t idxM = 0;

  auto load_chain = [&](int c, float& sp, float& dth, float& coef,
                        float& mag, float& phi, uint32_t& idx) {
    const int gi = base + c * EXPRN;
    const float a = amp[gi], p = phase[gi], d0 = decay[gi], pd = pdith[gi];
    const float sig = 1.0f / (1.0f + expf(-d0));
    const float coeff = 0.5f + 0.495f * sig;     // BASE_RES + sig*0.5*0.99
    coef = coeff;
    const float lgc = logf(coeff);
    const float smN = a * a * (1.0f / 1024.0f);  // fold 1/M irfft norm
    sp  = tanhf(p) * PI_F;
    dth = tanhf(pd);
    idx = (uint32_t)(b * NF) * (uint32_t)NC + (uint32_t)c;
    float acc = 0.0f;
    for (int s2 = 0; s2 < tstart; ++s2) { acc += tf_noise(idx); idx += NC; }
    phi = (float)tstart * sp + dth * acc;
    mag = smN * expf((float)tstart * lgc);
  };
  load_chain(k,         spA, dthA, coefA, magA, phiA, idxA);
  load_chain(MHALF - k, spB, dthB, coefB, magB, phiB, idxB);
  if (k == 0) load_chain(512, spM, dthM, coefM, magM, phiM, idxM);

  // per-thread pack twiddle e^{+i*pi*k/1024}
  float stk, ctk;
  sincosf(PI_F * (float)k * (1.0f / 1024.0f), &stk, &ctk);

  float carry0 = 0.0f, carry1 = 0.0f;           // OLA carry for m=tid, tid+512
  const long outbase = (long)b * (NF * HOP);
  const int krA = (int)(__brev((uint32_t)k) >> 22);
  const int krB = (int)(__brev((uint32_t)(MHALF - k)) >> 22);  // k=0: brev(1024) garbage, unused

  __syncthreads();

  for (int t = tstart; t < tend; ++t) {
    // ---- spectrum (registers) + pack + bit-reversed scatter ----
    { float nz = tf_noise(idxA); idxA += NC; phiA += spA + dthA * nz; magA *= coefA; }
    { float nz = tf_noise(idxB); idxB += NC; phiB += spB + dthB * nz; magB *= coefB; }
    float snA, csA; __sincosf(phiA, &snA, &csA);
    float snB, csB; __sincosf(phiB, &snB, &csB);
    const float x0r = magA * csA, x0i = (k == 0) ? 0.0f : magA * snA;  // c==0 imag zero
    const float x1r = magB * csB, x1i = (k == 0) ? 0.0f : magB * snB;  // c==1024 imag zero
    const float ar = 0.5f * (x0r + x1r);
    const float ai = 0.5f * (x0i - x1i);
    const float dr = x0r - x1r;
    const float di = x0i + x1i;
    const float br = -0.5f * (dr * stk + di * ctk);
    const float bi =  0.5f * (dr * ctk - di * stk);
    zr[F(krA)] = ar + br;
    zi[F(krA)] = ai + bi;
    if (k > 0) {
      zr[F(krB)] = ar - br;          // Z[1024-k] = (ar-br, bi-ai) by symmetry
      zi[F(krB)] = bi - ai;
    } else {
      // thread 0 also emits Z[512] = (X512.r, -X512.i); brev10(512) = 1
      float nz = tf_noise(idxM); idxM += NC; phiM += spM + dthM * nz; magM *= coefM;
      float snM, csM; __sincosf(phiM, &snM, &csM);
      zr[F(1)] =  magM * csM;
      zi[F(1)] = -magM * snM;
    }
    __syncthreads();

    // ---- 1024-pt radix-2 DIT inverse FFT (e^{+i}), packed twiddles ----
    for (int s = 1; s <= 10; ++s) {
      const int half = 1 << (s - 1);
      const int q  = tid >> (s - 1);
      const int rr = tid & (half - 1);
      const int i0 = (q << s) | rr;
      const int i1 = i0 + half;
      const float2 w = tw[half + rr];           // consecutive/broadcast: conflict-free
      const float ur = zr[F(i0)], ui = zi[F(i0)];
      const float vr = zr[F(i1)], vi = zi[F(i1)];
      const float tr  = vr * w.x - vi * w.y;
      const float ti2 = vr * w.y + vi * w.x;
      zr[F(i0)] = ur + tr;   zi[F(i0)] = ui + ti2;
      zr[F(i1)] = ur - tr;   zi[F(i1)] = ui - ti2;
      __syncthreads();
    }

    // ---- overlap-add: out[m] = frame[m] + prev_frame[1024+m]; carry 2nd half
    {
      const int m0 = tid, m1 = tid + 512;
      const float xa0 = (m0 & 1) ? zi[F(m0 >> 1)] : zr[F(m0 >> 1)];
      const float xa1 = (m1 & 1) ? zi[F(m1 >> 1)] : zr[F(m1 >> 1)];
      const float xb0 = (m0 & 1) ? zi[F((m0 + HOP) >> 1)] : zr[F((m0 + HOP) >> 1)];
      const float xb1 = (m1 & 1) ? zi[F((m1 + HOP) >> 1)] : zr[F((m1 + HOP) >> 1)];
      if (t >= t0) {
        const long ob = outbase + (long)t * HOP;
        out[ob + m0] = xa0 + carry0;
        out[ob + m1] = xa1 + carry1;
      }
      carry0 = xb0;
      carry1 = xb1;
    }
    __syncthreads();   // OLA reads must complete before next frame's scatter
  }
}

extern "C" void kernel_launch(void* const* d_in, const int* in_sizes, int n_in,
                              void* d_out, int out_size, void* d_ws, size_t ws_size,
                              hipStream_t stream) {
  (void)in_sizes; (void)n_in; (void)d_ws; (void)ws_size; (void)out_size;
  const float* amp   = (const float*)d_in[0];
  const float* phase = (const float*)d_in[1];
  const float* decay = (const float*)d_in[2];
  const float* pdith = (const float*)d_in[3];
  float* out = (float*)d_out;

  dim3 grid(B_TOT, NCHUNK);
  dim3 block(NTHREADS);
  hipLaunchKernelGGL(resblock_kernel, grid, block, 0, stream,
                     amp, phase, decay, pdith, out);
}